// Round 3
// baseline (2183.314 us; speedup 1.0000x reference)
//
#include <hip/hip_runtime.h>

#define BATCH 512
#define SEQ   1024
#define NT    64
#define NSEG  8
#define SEGLEN (SEQ / NSEG)   // 128
#define CH    4
#define NCHS  (SEGLEN / CH)   // 32

typedef float    f32x4 __attribute__((ext_vector_type(4)));
typedef _Float16 v8h   __attribute__((ext_vector_type(8)));
typedef _Float16 h2v   __attribute__((ext_vector_type(2)));
typedef int      int4v __attribute__((ext_vector_type(4)));

__device__ __forceinline__ int pkrtz_bits(float a, float b) {
    auto pk = __builtin_amdgcn_cvt_pkrtz(a, b);   // lo=a, hi=b
    return __builtin_bit_cast(int, pk);
}
__device__ __forceinline__ float exp2_hw(float x) {
    float r; asm("v_exp_f32 %0, %1" : "=v"(r) : "v"(x)); return r;
}
__device__ __forceinline__ float log2_hw(float x) {
    float r; asm("v_log_f32 %0, %1" : "=v"(r) : "v"(x)); return r;
}
// row_ror:n reductions within 16-lane rows. ctrl: 0x120+n = row_ror:n
#define DPP_MAX(x, ctrl) { int _t = __builtin_amdgcn_update_dpp( \
    __builtin_bit_cast(int,(x)), __builtin_bit_cast(int,(x)), (ctrl), 0xf, 0xf, false); \
    (x) = fmaxf((x), __builtin_bit_cast(float,_t)); }
#define DPP_ADD(x, ctrl) { int _t = __builtin_amdgcn_update_dpp( \
    __builtin_bit_cast(int,(x)), __builtin_bit_cast(int,(x)), (ctrl), 0xf, 0xf, false); \
    (x) += __builtin_bit_cast(float,_t); }

// Segmented matrix-product scan (round-2 verified structure), VALU-trimmed:
//  - NO per-step emissions max: rs = KGOV + 0.5*mlog2 only. The damped
//    feedback (poles 0.707) tracks growth; KGOV centers the f16 state at
//    ~2^-3 with ~18 log2 overflow headroom (worst-case |e|<=5.5 transient
//    peaks ~2^7 << 2^15.9).
//  - Governor max SAMPLED over col-tiles v in {0,1} (32/64 entries; G is
//    near rank-1 so delta < ~1 log2, absorbed by KGOV margin), max3-fused,
//    cross-lane = 4 DPP + 2 shfl.
//  - gseg LDS removed: the inter-segment stitch runs from register-held Bf
//    fragments in 8 barrier rounds. LDS < 1 KB; launch_bounds(512,4) caps
//    VGPR at 128 -> 2 blocks/CU resident.
__global__ __launch_bounds__(512, 4) void crf_kernel(
        const float* __restrict__ emis,
        const int*   __restrict__ tags,
        const float* __restrict__ mask,
        const float* __restrict__ trans,
        float*       __restrict__ out)
{
    const int b   = blockIdx.x;
    const int tid = threadIdx.x;
    const int seg = tid >> 6;
    const int l   = tid & 63;
    const int cc  = l & 15;
    const int q   = l >> 4;

    __shared__ float ubuf[NT];
    __shared__ float gred[NSEG];
    __shared__ float sigma_sh;

    if (tid < NT) ubuf[tid] = 1.0f;
    if (tid == 0) sigma_sh = 0.0f;

    const float INVLN2 = 1.44269504088896340736f;
    const float LN2    = 0.69314718055994530942f;
    const float KGOV   = 10.26f;   // E[max64 N(0,1)]*log2e + 6.2 + margin
    const f32x4 zero4  = {0.f, 0.f, 0.f, 0.f};

    // ---- static A fragments: A0[mt][h] holds E[rho(h,q,e)][16mt+cc] f16 pairs ----
    v8h A0[4][2];
    #pragma unroll
    for (int mt = 0; mt < 4; ++mt) {
        #pragma unroll
        for (int h = 0; h < 2; ++h) {
            int4v pv;
            #pragma unroll
            for (int r2 = 0; r2 < 4; ++r2) {
                const int row0 = 16 * (2*h + (r2 >> 1)) + 4*q + 2*(r2 & 1);
                const int colm = 16 * mt + cc;
                pv[r2] = pkrtz_bits(__expf(trans[row0 * NT + colm]),
                                    __expf(trans[(row0 + 1) * NT + colm]));
            }
            A0[mt][h] = __builtin_bit_cast(v8h, pv);
        }
    }

    // ---- B = G_0 = Identity, directly in fragment form ----
    v8h Bf[4][2];
    #pragma unroll
    for (int v = 0; v < 4; ++v) {
        #pragma unroll
        for (int h = 0; h < 2; ++h) {
            int4v pv;
            #pragma unroll
            for (int r2 = 0; r2 < 4; ++r2) {
                const int row0 = 16 * (2*h + (r2 >> 1)) + 4*q + 2*(r2 & 1);
                const int col  = 4 * cc + v;
                unsigned lo = (row0 == col)     ? 0x3C00u : 0u;
                unsigned hi = (row0 + 1 == col) ? 0x3C00u : 0u;
                pv[r2] = (int)(lo | (hi << 16));
            }
            Bf[v][h] = __builtin_bit_cast(v8h, pv);
        }
    }

    f32x4 acc[4][4];
    float ls = 0.0f, mlog1 = 0.0f, mlog2 = 0.0f;

    const float* ebase = emis + (size_t)b * SEQ * NT + (size_t)seg * SEGLEN * NT;
    const float* mbase = mask + (size_t)b * SEQ + seg * SEGLEN;

#define LOADCHUNK(c, E, MV) { \
    _Pragma("unroll") \
    for (int t2 = 0; t2 < CH; ++t2) { \
        _Pragma("unroll") \
        for (int mt = 0; mt < 4; ++mt) \
            E[t2*4 + mt] = ebase[((c)*CH + t2) * NT + 16*mt + cc]; } \
    MV = *(const f32x4*)(mbase + (c) * CH); }

#define ALLONE(MV) ((MV[0]==1.0f) & (MV[1]==1.0f) & (MV[2]==1.0f) & (MV[3]==1.0f))

#define STEP(E, MV, ts, A1) { \
    const float e0 = E[(ts)*4+0], e1 = E[(ts)*4+1], e2 = E[(ts)*4+2], e3 = E[(ts)*4+3]; \
    const float mk = MV[ts]; \
    const float rs = fmaf(0.5f, mlog2, KGOV); \
    ls += rs; \
    const float d0 = exp2_hw(fmaf(e0, INVLN2, -rs)); \
    const float d1 = exp2_hw(fmaf(e1, INVLN2, -rs)); \
    const float d2 = exp2_hw(fmaf(e2, INVLN2, -rs)); \
    const float d3 = exp2_hw(fmaf(e3, INVLN2, -rs)); \
    int spk[4]; \
    spk[0] = pkrtz_bits(d0, d0); spk[1] = pkrtz_bits(d1, d1); \
    spk[2] = pkrtz_bits(d2, d2); spk[3] = pkrtz_bits(d3, d3); \
    _Pragma("unroll") \
    for (int mt = 0; mt < 4; ++mt) { \
        int4v sq = { spk[mt], spk[mt], spk[mt], spk[mt] }; \
        const v8h sv  = __builtin_bit_cast(v8h, sq); \
        const v8h As0 = A0[mt][0] * sv; \
        const v8h As1 = A0[mt][1] * sv; \
        _Pragma("unroll") \
        for (int v = 0; v < 4; ++v) \
            acc[mt][v] = __builtin_amdgcn_mfma_f32_16x16x32_f16(As1, Bf[v][1], \
                         __builtin_amdgcn_mfma_f32_16x16x32_f16(As0, Bf[v][0], zero4, 0,0,0), 0,0,0); \
    } \
    if (!(A1) && mk != 1.0f) {  /* generic mask blend (all-ones: never taken) */ \
        const float g2 = exp2_hw(-rs), om = 1.0f - mk; \
        _Pragma("unroll") \
        for (int v = 0; v < 4; ++v) { \
            _Pragma("unroll") \
            for (int h = 0; h < 2; ++h) { \
                const int4v bb = __builtin_bit_cast(int4v, Bf[v][h]); \
                _Pragma("unroll") \
                for (int r2 = 0; r2 < 4; ++r2) { \
                    const int mt = 2*h + (r2 >> 1), rr = 2*(r2 & 1); \
                    const h2v gh = __builtin_bit_cast(h2v, bb[r2]); \
                    acc[mt][v][rr]   = mk * acc[mt][v][rr]   + om * g2 * (float)gh.x; \
                    acc[mt][v][rr+1] = mk * acc[mt][v][rr+1] + om * g2 * (float)gh.y; \
                } } } } \
    float M = 0.0f; \
    _Pragma("unroll") \
    for (int mt = 0; mt < 4; ++mt) { \
        _Pragma("unroll") \
        for (int v = 0; v < 2; ++v) { \
            const f32x4 a = acc[mt][v]; \
            M = fmaxf(M, fmaxf(fmaxf(a.x, a.y), fmaxf(a.z, a.w))); } } \
    DPP_MAX(M, 0x128) DPP_MAX(M, 0x124) DPP_MAX(M, 0x122) DPP_MAX(M, 0x121) \
    M = fmaxf(M, __shfl_xor(M, 16, 64)); \
    M = fmaxf(M, __shfl_xor(M, 32, 64)); \
    mlog2 = mlog1; mlog1 = log2_hw(M); \
    _Pragma("unroll") \
    for (int v = 0; v < 4; ++v) { \
        _Pragma("unroll") \
        for (int h = 0; h < 2; ++h) { \
            int4v nb; \
            _Pragma("unroll") \
            for (int r2 = 0; r2 < 4; ++r2) { \
                const int mt = 2*h + (r2 >> 1), rr = 2*(r2 & 1); \
                nb[r2] = pkrtz_bits(acc[mt][v][rr], acc[mt][v][rr+1]); } \
            Bf[v][h] = __builtin_bit_cast(v8h, nb); } } }

    float eA[16], eB[16];
    f32x4 mA, mB;
    LOADCHUNK(0, eA, mA);
    #pragma unroll 1
    for (int c = 0; c < NCHS; c += 2) {
        LOADCHUNK(c + 1, eB, mB);
        const bool a1A = ALLONE(mA);
        STEP(eA, mA, 0, a1A) STEP(eA, mA, 1, a1A) STEP(eA, mA, 2, a1A) STEP(eA, mA, 3, a1A)
        if (c + 2 < NCHS) LOADCHUNK(c + 2, eA, mA);
        const bool a1B = ALLONE(mB);
        STEP(eB, mB, 0, a1B) STEP(eB, mB, 1, a1B) STEP(eB, mB, 2, a1B) STEP(eB, mB, 3, a1B)
    }

    // ---- gold scores (all 512 threads; written before the stitch barriers) ----
    {
        const int*   tb  = tags + (size_t)b * SEQ;
        const float* ebm = emis + (size_t)b * SEQ * NT;
        const float* mbm = mask + (size_t)b * SEQ;
        float acg = 0.0f;
        for (int s = 1 + tid; s < SEQ; s += NSEG * 64) {
            const int tc = tb[s];
            const int tp = tb[s - 1];
            acg += (ebm[(size_t)s * NT + tc] + trans[tp * NT + tc]) * mbm[s];
        }
        acg += __shfl_xor(acg, 32, 64); acg += __shfl_xor(acg, 16, 64);
        acg += __shfl_xor(acg,  8, 64); acg += __shfl_xor(acg,  4, 64);
        acg += __shfl_xor(acg,  2, 64); acg += __shfl_xor(acg,  1, 64);
        if (l == 0) gred[seg] = acg;
    }

    // ---- stitch: 8 barrier rounds, u <- G_s u from register fragments ----
    #pragma unroll 1
    for (int s = 0; s < NSEG; ++s) {
        __syncthreads();
        if (seg == s) {
            float u4[4];
            #pragma unroll
            for (int v = 0; v < 4; ++v) u4[v] = ubuf[4*cc + v];
            float p[16];
            #pragma unroll
            for (int h = 0; h < 2; ++h) {
                #pragma unroll
                for (int e = 0; e < 8; ++e) {
                    float a2 = 0.0f;
                    #pragma unroll
                    for (int v = 0; v < 4; ++v)
                        a2 = fmaf((float)Bf[v][h][e], u4[v], a2);
                    p[h*8 + e] = a2;
                }
            }
            #pragma unroll
            for (int i = 0; i < 16; ++i) {
                DPP_ADD(p[i], 0x128) DPP_ADD(p[i], 0x124)
                DPP_ADD(p[i], 0x122) DPP_ADD(p[i], 0x121)
            }
            float pm = p[0];
            #pragma unroll
            for (int i = 1; i < 16; ++i) pm = fmaxf(pm, p[i]);
            pm = fmaxf(pm, __shfl_xor(pm, 16, 64));
            pm = fmaxf(pm, __shfl_xor(pm, 32, 64));
            const float rpm = 1.0f / pm;
            if (cc == 0) {
                #pragma unroll
                for (int h = 0; h < 2; ++h)
                    #pragma unroll
                    for (int e = 0; e < 8; ++e)
                        ubuf[16*(2*h + (e>>2)) + 4*q + (e&3)] = p[h*8 + e] * rpm;
            }
            if (l == 0) sigma_sh += log2_hw(pm) + ls;
        }
    }
    __syncthreads();

    // ---- final: Z and output ----
    if (seg == 0) {
        float su = ubuf[l];
        su += __shfl_xor(su, 32, 64); su += __shfl_xor(su, 16, 64);
        su += __shfl_xor(su,  8, 64); su += __shfl_xor(su,  4, 64);
        su += __shfl_xor(su,  2, 64); su += __shfl_xor(su,  1, 64);
        const float Z = LN2 * (sigma_sh + log2_hw(su));
        float gold = 0.0f;
        #pragma unroll
        for (int s = 0; s < NSEG; ++s) gold += gred[s];
        if (l == 0)
            atomicAdd(out, (gold - Z) * (1.0f / BATCH));
    }
}

__global__ void zero_kernel(float* out) { if (threadIdx.x == 0) out[0] = 0.0f; }

extern "C" void kernel_launch(void* const* d_in, const int* in_sizes, int n_in,
                              void* d_out, int out_size, void* d_ws, size_t ws_size,
                              hipStream_t stream) {
    const float* emis  = (const float*)d_in[0];
    const int*   tags  = (const int*)d_in[1];
    const float* mask  = (const float*)d_in[2];
    const float* trans = (const float*)d_in[3];
    float* out = (float*)d_out;

    zero_kernel<<<1, 64, 0, stream>>>(out);
    crf_kernel<<<BATCH, NSEG * 64, 0, stream>>>(emis, tags, mask, trans, out);
}

// Round 4
// 453.602 us; speedup vs baseline: 4.8133x; 4.8133x over previous
//
#include <hip/hip_runtime.h>

#define BATCH 512
#define SEQ   1024
#define NT    64
#define NSEG  8
#define SEGLEN (SEQ / NSEG)   // 128
#define NCHG  (SEGLEN / 4)    // 32 chunks of 4 steps

typedef float    f32x4 __attribute__((ext_vector_type(4)));
typedef _Float16 v8h   __attribute__((ext_vector_type(8)));
typedef _Float16 h2v   __attribute__((ext_vector_type(2)));
typedef int      int4v __attribute__((ext_vector_type(4)));

__device__ __forceinline__ int pkrtz_bits(float a, float b) {
    auto pk = __builtin_amdgcn_cvt_pkrtz(a, b);   // lo=a, hi=b
    return __builtin_bit_cast(int, pk);
}
__device__ __forceinline__ float exp2_hw(float x) {
    float r; asm("v_exp_f32 %0, %1" : "=v"(r) : "v"(x)); return r;
}
__device__ __forceinline__ float log2_hw(float x) {
    float r; asm("v_log_f32 %0, %1" : "=v"(r) : "v"(x)); return r;
}
#define DPP_MAX(x, ctrl) { int _t = __builtin_amdgcn_update_dpp( \
    __builtin_bit_cast(int,(x)), __builtin_bit_cast(int,(x)), (ctrl), 0xf, 0xf, false); \
    (x) = fmaxf((x), __builtin_bit_cast(float,_t)); }
#define DPP_ADD(x, ctrl) { int _t = __builtin_amdgcn_update_dpp( \
    __builtin_bit_cast(int,(x)), __builtin_bit_cast(int,(x)), (ctrl), 0xf, 0xf, false); \
    (x) += __builtin_bit_cast(float,_t); }

#define GLDS16(gsrc, ldst) \
    __builtin_amdgcn_global_load_lds( \
        (const __attribute__((address_space(1))) unsigned int*)(gsrc), \
        (__attribute__((address_space(3))) unsigned int*)(ldst), 16, 0, 0)
#define GLDS4(gsrc, ldst) \
    __builtin_amdgcn_global_load_lds( \
        (const __attribute__((address_space(1))) unsigned int*)(gsrc), \
        (__attribute__((address_space(3))) unsigned int*)(ldst), 4, 0, 0)

// Segmented matrix-product scan (round-2/3 verified math). This round:
//  - Diagonal moved to the OUTPUT side: G' = D*(E^T G). MFMA uses fully
//    STATIC A0 (no f16 vector arithmetic in the loop at all); the scale is
//    64 f32 muls on the accumulator (guaranteed 1-instr each), fused into
//    the repack path. C-layout algebra: acc[mt][v][rr] = row 16mt+4q+rr,
//    col 4cc+v  => d indexed (mt,rr) per-lane via q, loaded as f32x4.
//  - d is computed ONE STEP AHEAD (depends only on prefetched e and the
//    lag-2 governor) -> off the serial spine.
//  - e staged via GLDS16 into a 4-buffer LDS ring, issued 2 chunks ahead,
//    counted vmcnt(1) (never 0 in loop). mask staged whole-segment once.
//  - launch_bounds(512,1): round-3's (512,4) forced a 128-reg cap and
//    spilled everything (7 GB scratch traffic). State needs ~220 regs.
__global__ __launch_bounds__(512, 1) void crf_kernel(
        const float* __restrict__ emis,
        const int*   __restrict__ tags,
        const float* __restrict__ mask,
        const float* __restrict__ trans,
        float*       __restrict__ out)
{
    const int b   = blockIdx.x;
    const int tid = threadIdx.x;
    const int seg = tid >> 6;
    const int l   = tid & 63;
    const int cc  = l & 15;
    const int q   = l >> 4;

    __shared__ float etile[NSEG][4][256];   // 32 KB: 4-deep e-chunk ring / wave
    __shared__ float mtile[NSEG][SEGLEN];   // 4 KB: whole-segment mask / wave
    __shared__ float ubuf[NT];
    __shared__ float gred[NSEG];
    __shared__ float sigma_sh;

    if (tid < NT) ubuf[tid] = 1.0f;
    if (tid == 0) sigma_sh = 0.0f;

    const float INVLN2 = 1.44269504088896340736f;
    const float LN2    = 0.69314718055994530942f;
    const float KGOV   = 10.26f;
    const f32x4 zero4  = {0.f, 0.f, 0.f, 0.f};

    // ---- static A fragments: A0[mt][h] holds E[rho(h,q,e)][16mt+cc] ----
    v8h A0[4][2];
    #pragma unroll
    for (int mt = 0; mt < 4; ++mt) {
        #pragma unroll
        for (int h = 0; h < 2; ++h) {
            int4v pv;
            #pragma unroll
            for (int r2 = 0; r2 < 4; ++r2) {
                const int row0 = 16 * (2*h + (r2 >> 1)) + 4*q + 2*(r2 & 1);
                const int colm = 16 * mt + cc;
                pv[r2] = pkrtz_bits(__expf(trans[row0 * NT + colm]),
                                    __expf(trans[(row0 + 1) * NT + colm]));
            }
            A0[mt][h] = __builtin_bit_cast(v8h, pv);
        }
    }

    // ---- B = G_0 = Identity in fragment form ----
    v8h Bf[4][2];
    #pragma unroll
    for (int v = 0; v < 4; ++v) {
        #pragma unroll
        for (int h = 0; h < 2; ++h) {
            int4v pv;
            #pragma unroll
            for (int r2 = 0; r2 < 4; ++r2) {
                const int row0 = 16 * (2*h + (r2 >> 1)) + 4*q + 2*(r2 & 1);
                const int col  = 4 * cc + v;
                unsigned lo = (row0 == col)     ? 0x3C00u : 0u;
                unsigned hi = (row0 + 1 == col) ? 0x3C00u : 0u;
                pv[r2] = (int)(lo | (hi << 16));
            }
            Bf[v][h] = __builtin_bit_cast(v8h, pv);
        }
    }

    const float* ebase = emis + (size_t)b * SEQ * NT + (size_t)seg * SEGLEN * NT;
    const float* mbase = mask + (size_t)b * SEQ + seg * SEGLEN;
    const float* etbl  = &etile[seg][0][0];

    // ---- prologue staging: chunks 0,1 + whole-segment mask ----
    GLDS16(ebase + l * 4,       &etile[seg][0][0]);
    GLDS16(ebase + 256 + l * 4, &etile[seg][1][0]);
    GLDS4(mbase + l,      &mtile[seg][0]);
    GLDS4(mbase + 64 + l, &mtile[seg][64]);
    asm volatile("s_waitcnt vmcnt(0)" ::: "memory");

    float ls = 0.0f, mlog1 = 0.0f, rs_use = KGOV;
    f32x4 dA4[4], dB4[4];
    #pragma unroll
    for (int mt = 0; mt < 4; ++mt) {
        const f32x4 ev0 = *(const f32x4*)(etbl + 16*mt + 4*q);
        #pragma unroll
        for (int rr = 0; rr < 4; ++rr)
            dA4[mt][rr] = exp2_hw(fmaf(ev0[rr], INVLN2, -KGOV));
    }

#define STEP(DIN, DOUT, TS) { \
    f32x4 acc_[4][4]; \
    _Pragma("unroll") \
    for (int mt = 0; mt < 4; ++mt) { \
        _Pragma("unroll") \
        for (int v = 0; v < 4; ++v) \
            acc_[mt][v] = __builtin_amdgcn_mfma_f32_16x16x32_f16(A0[mt][1], Bf[v][1], \
                          __builtin_amdgcn_mfma_f32_16x16x32_f16(A0[mt][0], Bf[v][0], zero4, 0,0,0), 0,0,0); \
    } \
    const float rsF = fmaf(0.5f, mlog1, KGOV); \
    { const float* evp_ = etbl + (((g + (((TS)+1) >> 2)) & 3) * 256) + ((((TS)+1) & 3) * 64) + 4*q; \
      _Pragma("unroll") \
      for (int mt = 0; mt < 4; ++mt) { \
          const f32x4 ev_ = *(const f32x4*)(evp_ + 16*mt); \
          _Pragma("unroll") \
          for (int rr = 0; rr < 4; ++rr) \
              DOUT[mt][rr] = exp2_hw(fmaf(ev_[rr], INVLN2, -rsF)); } } \
    _Pragma("unroll") \
    for (int mt = 0; mt < 4; ++mt) { \
        _Pragma("unroll") \
        for (int v = 0; v < 4; ++v) \
            acc_[mt][v] *= DIN[mt]; \
    } \
    const float mk_ = mk4[TS]; \
    if (!a1_ && mk_ != 1.0f) { \
        const float g2_ = exp2_hw(-rs_use), om_ = 1.0f - mk_; \
        _Pragma("unroll") \
        for (int v = 0; v < 4; ++v) { \
            _Pragma("unroll") \
            for (int h = 0; h < 2; ++h) { \
                const int4v bb_ = __builtin_bit_cast(int4v, Bf[v][h]); \
                _Pragma("unroll") \
                for (int r2 = 0; r2 < 4; ++r2) { \
                    const int mt_ = 2*h + (r2 >> 1), rr_ = 2*(r2 & 1); \
                    const h2v gh_ = __builtin_bit_cast(h2v, bb_[r2]); \
                    acc_[mt_][v][rr_]   = mk_ * acc_[mt_][v][rr_]   + om_ * g2_ * (float)gh_.x; \
                    acc_[mt_][v][rr_+1] = mk_ * acc_[mt_][v][rr_+1] + om_ * g2_ * (float)gh_.y; \
                } } } } \
    f32x4 mx_ = acc_[0][0]; \
    _Pragma("unroll") \
    for (int rr = 0; rr < 4; ++rr) mx_[rr] = fmaxf(mx_[rr], acc_[0][1][rr]); \
    _Pragma("unroll") \
    for (int mt = 1; mt < 4; ++mt) { \
        _Pragma("unroll") \
        for (int rr = 0; rr < 4; ++rr) \
            mx_[rr] = fmaxf(mx_[rr], fmaxf(acc_[mt][0][rr], acc_[mt][1][rr])); } \
    float M_ = fmaxf(fmaxf(mx_[0], mx_[1]), fmaxf(mx_[2], mx_[3])); \
    DPP_MAX(M_, 0x128) DPP_MAX(M_, 0x124) DPP_MAX(M_, 0x122) DPP_MAX(M_, 0x121) \
    M_ = fmaxf(M_, __shfl_xor(M_, 16, 64)); \
    M_ = fmaxf(M_, __shfl_xor(M_, 32, 64)); \
    ls += rs_use; rs_use = rsF; mlog1 = log2_hw(M_); \
    _Pragma("unroll") \
    for (int v = 0; v < 4; ++v) { \
        _Pragma("unroll") \
        for (int h = 0; h < 2; ++h) { \
            int4v nb_; \
            _Pragma("unroll") \
            for (int r2 = 0; r2 < 4; ++r2) { \
                const int mt_ = 2*h + (r2 >> 1), rr_ = 2*(r2 & 1); \
                nb_[r2] = pkrtz_bits(acc_[mt_][v][rr_], acc_[mt_][v][rr_+1]); } \
            Bf[v][h] = __builtin_bit_cast(v8h, nb_); } } }

    #pragma unroll 1
    for (int g = 0; g < NCHG; ++g) {
        if (g + 2 < NCHG) {
            GLDS16(ebase + (g + 2) * 256 + l * 4, &etile[seg][(g + 2) & 3][0]);
            asm volatile("s_waitcnt vmcnt(1)" ::: "memory");   // chunk g+1 landed
        } else {
            asm volatile("s_waitcnt vmcnt(0)" ::: "memory");
        }
        const f32x4 mk4 = *(const f32x4*)&mtile[seg][4 * g];
        const bool a1_ = (mk4[0] == 1.0f) & (mk4[1] == 1.0f) &
                         (mk4[2] == 1.0f) & (mk4[3] == 1.0f);
        STEP(dA4, dB4, 0) STEP(dB4, dA4, 1) STEP(dA4, dB4, 2) STEP(dB4, dA4, 3)
    }

    // ---- gold scores ----
    {
        const int*   tb  = tags + (size_t)b * SEQ;
        const float* ebm = emis + (size_t)b * SEQ * NT;
        const float* mbm = mask + (size_t)b * SEQ;
        float acg = 0.0f;
        for (int s = 1 + tid; s < SEQ; s += NSEG * 64) {
            const int tc = tb[s];
            const int tp = tb[s - 1];
            acg += (ebm[(size_t)s * NT + tc] + trans[tp * NT + tc]) * mbm[s];
        }
        acg += __shfl_xor(acg, 32, 64); acg += __shfl_xor(acg, 16, 64);
        acg += __shfl_xor(acg,  8, 64); acg += __shfl_xor(acg,  4, 64);
        acg += __shfl_xor(acg,  2, 64); acg += __shfl_xor(acg,  1, 64);
        if (l == 0) gred[seg] = acg;
    }

    // ---- stitch: 8 barrier rounds, u <- G_s u from register fragments ----
    #pragma unroll 1
    for (int s = 0; s < NSEG; ++s) {
        __syncthreads();
        if (seg == s) {
            float u4[4];
            #pragma unroll
            for (int v = 0; v < 4; ++v) u4[v] = ubuf[4*cc + v];
            float p[16];
            #pragma unroll
            for (int h = 0; h < 2; ++h) {
                #pragma unroll
                for (int e = 0; e < 8; ++e) {
                    float a2 = 0.0f;
                    #pragma unroll
                    for (int v = 0; v < 4; ++v)
                        a2 = fmaf((float)Bf[v][h][e], u4[v], a2);
                    p[h*8 + e] = a2;
                }
            }
            #pragma unroll
            for (int i = 0; i < 16; ++i) {
                DPP_ADD(p[i], 0x128) DPP_ADD(p[i], 0x124)
                DPP_ADD(p[i], 0x122) DPP_ADD(p[i], 0x121)
            }
            float pm = p[0];
            #pragma unroll
            for (int i = 1; i < 16; ++i) pm = fmaxf(pm, p[i]);
            pm = fmaxf(pm, __shfl_xor(pm, 16, 64));
            pm = fmaxf(pm, __shfl_xor(pm, 32, 64));
            const float rpm = 1.0f / pm;
            if (cc == 0) {
                #pragma unroll
                for (int h = 0; h < 2; ++h)
                    #pragma unroll
                    for (int e = 0; e < 8; ++e)
                        ubuf[16*(2*h + (e>>2)) + 4*q + (e&3)] = p[h*8 + e] * rpm;
            }
            if (l == 0) sigma_sh += log2_hw(pm) + ls;
        }
    }
    __syncthreads();

    // ---- final: Z and output ----
    if (seg == 0) {
        float su = ubuf[l];
        su += __shfl_xor(su, 32, 64); su += __shfl_xor(su, 16, 64);
        su += __shfl_xor(su,  8, 64); su += __shfl_xor(su,  4, 64);
        su += __shfl_xor(su,  2, 64); su += __shfl_xor(su,  1, 64);
        const float Z = LN2 * (sigma_sh + log2_hw(su));
        float gold = 0.0f;
        #pragma unroll
        for (int s = 0; s < NSEG; ++s) gold += gred[s];
        if (l == 0)
            atomicAdd(out, (gold - Z) * (1.0f / BATCH));
    }
}

__global__ void zero_kernel(float* out) { if (threadIdx.x == 0) out[0] = 0.0f; }

extern "C" void kernel_launch(void* const* d_in, const int* in_sizes, int n_in,
                              void* d_out, int out_size, void* d_ws, size_t ws_size,
                              hipStream_t stream) {
    const float* emis  = (const float*)d_in[0];
    const int*   tags  = (const int*)d_in[1];
    const float* mask  = (const float*)d_in[2];
    const float* trans = (const float*)d_in[3];
    float* out = (float*)d_out;

    zero_kernel<<<1, 64, 0, stream>>>(out);
    crf_kernel<<<BATCH, NSEG * 64, 0, stream>>>(emis, tags, mask, trans, out);
}

// Round 5
// 392.137 us; speedup vs baseline: 5.5677x; 1.1567x over previous
//
#include <hip/hip_runtime.h>

#define BATCH 512
#define SEQ   1024
#define NT    64
#define NSEG  4
#define SEGLEN (SEQ / NSEG)   // 256
#define NCHG  (SEGLEN / 4)    // 64 chunks of 4 steps

typedef float    f32x4 __attribute__((ext_vector_type(4)));
typedef _Float16 v8h   __attribute__((ext_vector_type(8)));
typedef _Float16 h2v   __attribute__((ext_vector_type(2)));
typedef int      int4v __attribute__((ext_vector_type(4)));

__device__ __forceinline__ int pkrtz_bits(float a, float b) {
    auto pk = __builtin_amdgcn_cvt_pkrtz(a, b);   // lo=a, hi=b
    return __builtin_bit_cast(int, pk);
}
__device__ __forceinline__ float exp2_hw(float x) {
    float r; asm("v_exp_f32 %0, %1" : "=v"(r) : "v"(x)); return r;
}
__device__ __forceinline__ float log2_hw(float x) {
    float r; asm("v_log_f32 %0, %1" : "=v"(r) : "v"(x)); return r;
}
__device__ __forceinline__ int frexp_exp_hw(float x) {
    int r; asm("v_frexp_exp_i32_f32 %0, %1" : "=v"(r) : "v"(x)); return r;
}
#define DPP_ADD(x, ctrl) { int _t = __builtin_amdgcn_update_dpp( \
    __builtin_bit_cast(int,(x)), __builtin_bit_cast(int,(x)), (ctrl), 0xf, 0xf, false); \
    (x) += __builtin_bit_cast(float,_t); }

#define GLDS16(gsrc, ldst) \
    __builtin_amdgcn_global_load_lds( \
        (const __attribute__((address_space(1))) unsigned int*)(gsrc), \
        (__attribute__((address_space(3))) unsigned int*)(ldst), 16, 0, 0)
#define GLDS4(gsrc, ldst) \
    __builtin_amdgcn_global_load_lds( \
        (const __attribute__((address_space(1))) unsigned int*)(gsrc), \
        (__attribute__((address_space(3))) unsigned int*)(ldst), 4, 0, 0)

// Segmented matrix-product scan, COLUMN-SPLIT: G's columns are independent
// through G <- D*(E^T G), so each segment is computed by TWO waves, each
// owning 32 columns (v-tiles {2hf, 2hf+1}). Per-wave register state:
// A0 32 + Bf 16 + acc 32 + temps ~= 112 unified VGPR+AGPR < 128
// -> __launch_bounds__(512,4) gives 4 waves/SIMD resident (round-4 was
// stuck at 2/SIMD: 108 VGPR + 64 AGPR = 172). 512 blocks x 8 waves =
// 4096 waves = exact machine fill at 4/SIMD, single 256-step pass.
// Governor: frexp_exp(acc[0][0][0]) + readfirstlane (no shuffle chain),
// lag-2, damping 0.5 (poles 0.707, same stability as verified rounds).
// Per-half scale ledgers ls reconciled in the stitch via 2^(L0-L1).
__global__ __launch_bounds__(512, 4) void crf_kernel(
        const float* __restrict__ emis,
        const int*   __restrict__ tags,
        const float* __restrict__ mask,
        const float* __restrict__ trans,
        float*       __restrict__ out)
{
    const int b   = blockIdx.x;
    const int tid = threadIdx.x;
    const int w   = tid >> 6;       // wave 0..7
    const int seg = w >> 1;         // segment 0..3
    const int hf  = w & 1;          // column half 0..1
    const int l   = tid & 63;
    const int cc  = l & 15;
    const int q   = l >> 4;

    __shared__ float ering[8][4][256];   // 32 KB: per-wave 4-deep e-chunk ring
    __shared__ float mtile[8][256];      // 8 KB: per-wave segment mask
    __shared__ float ph[2][NT];
    __shared__ float ubuf[NT];
    __shared__ float lsw[8];
    __shared__ float gredw[8];
    __shared__ float sigma_sh;

    if (tid < NT) ubuf[tid] = 1.0f;
    if (tid == 0) sigma_sh = 0.0f;

    const float INVLN2 = 1.44269504088896340736f;
    const float LN2    = 0.69314718055994530942f;
    const float CBASE  = 6.4f;    // steady growth ~6.9 log2/step -> proxy ~2^1
    const f32x4 zero4  = {0.f, 0.f, 0.f, 0.f};

    const float* ebase = emis + (size_t)b * SEQ * NT + (size_t)seg * SEGLEN * NT;
    const float* mbase = mask + (size_t)b * SEQ + seg * SEGLEN;

    // ---- prologue staging: whole-seg mask + e-chunks 0,1 ----
    GLDS4(mbase + l,       &mtile[w][0]);
    GLDS4(mbase + 64 + l,  &mtile[w][64]);
    GLDS4(mbase + 128 + l, &mtile[w][128]);
    GLDS4(mbase + 192 + l, &mtile[w][192]);
    GLDS16(ebase + 4 * l,       &ering[w][0][0]);
    GLDS16(ebase + 256 + 4 * l, &ering[w][1][0]);

    // ---- static A fragments: A0[mt][h][e] = exp(T)[rho(h,q,e)][16mt+cc] ----
    v8h A0[4][2];
    #pragma unroll
    for (int mt = 0; mt < 4; ++mt) {
        #pragma unroll
        for (int h = 0; h < 2; ++h) {
            int4v pv;
            #pragma unroll
            for (int r2 = 0; r2 < 4; ++r2) {
                const int row0 = 16 * (2*h + (r2 >> 1)) + 4*q + 2*(r2 & 1);
                const int colm = 16 * mt + cc;
                pv[r2] = pkrtz_bits(__expf(trans[row0 * NT + colm]),
                                    __expf(trans[(row0 + 1) * NT + colm]));
            }
            A0[mt][h] = __builtin_bit_cast(v8h, pv);
        }
    }

    // ---- B = identity columns of this wave's half: v = 2*hf + vt ----
    v8h Bf[2][2];
    #pragma unroll
    for (int vt = 0; vt < 2; ++vt) {
        #pragma unroll
        for (int h = 0; h < 2; ++h) {
            int4v pv;
            #pragma unroll
            for (int r2 = 0; r2 < 4; ++r2) {
                const int row0 = 16 * (2*h + (r2 >> 1)) + 4*q + 2*(r2 & 1);
                const int col  = 4 * cc + 2*hf + vt;
                unsigned lo = (row0 == col)     ? 0x3C00u : 0u;
                unsigned hi = (row0 + 1 == col) ? 0x3C00u : 0u;
                pv[r2] = (int)(lo | (hi << 16));
            }
            Bf[vt][h] = __builtin_bit_cast(v8h, pv);
        }
    }

    asm volatile("s_waitcnt vmcnt(1)" ::: "memory");   // mask + chunk0 landed

    float ls = 0.0f, exlag1 = 0.0f, exlag2 = 0.0f;

#define STEP(EP, G, TS) { \
    const float rs = fmaf(0.5f, exlag2, CBASE); \
    ls += rs; \
    int dup[4]; \
    _Pragma("unroll") \
    for (int mt = 0; mt < 4; ++mt) { \
        const float ev = (EP)[(TS)*64 + 16*mt + cc]; \
        const float d  = exp2_hw(fmaf(ev, INVLN2, -rs)); \
        dup[mt] = pkrtz_bits(d, d); \
    } \
    f32x4 acc[4][2]; \
    _Pragma("unroll") \
    for (int mt = 0; mt < 4; ++mt) { \
        int4v sq = { dup[mt], dup[mt], dup[mt], dup[mt] }; \
        const v8h dv  = __builtin_bit_cast(v8h, sq); \
        const v8h As0 = A0[mt][0] * dv; \
        const v8h As1 = A0[mt][1] * dv; \
        _Pragma("unroll") \
        for (int vt = 0; vt < 2; ++vt) \
            acc[mt][vt] = __builtin_amdgcn_mfma_f32_16x16x32_f16(As1, Bf[vt][1], \
                          __builtin_amdgcn_mfma_f32_16x16x32_f16(As0, Bf[vt][0], zero4, 0,0,0), 0,0,0); \
    } \
    const int exi = frexp_exp_hw(acc[0][0][0]); \
    const float exf = (float)__builtin_amdgcn_readfirstlane(exi); \
    exlag2 = exlag1; exlag1 = exf; \
    const float mk = mtile[w][4*(G) + (TS)]; \
    if (mk != 1.0f) { \
        const float g2 = exp2_hw(-rs), om = 1.0f - mk; \
        _Pragma("unroll") \
        for (int vt = 0; vt < 2; ++vt) { \
            _Pragma("unroll") \
            for (int h = 0; h < 2; ++h) { \
                const int4v bb = __builtin_bit_cast(int4v, Bf[vt][h]); \
                _Pragma("unroll") \
                for (int r2 = 0; r2 < 4; ++r2) { \
                    const int mt_ = 2*h + (r2 >> 1), rr_ = 2*(r2 & 1); \
                    const h2v gh = __builtin_bit_cast(h2v, bb[r2]); \
                    acc[mt_][vt][rr_]   = mk * acc[mt_][vt][rr_]   + om * g2 * (float)gh.x; \
                    acc[mt_][vt][rr_+1] = mk * acc[mt_][vt][rr_+1] + om * g2 * (float)gh.y; \
                } } } } \
    _Pragma("unroll") \
    for (int vt = 0; vt < 2; ++vt) { \
        _Pragma("unroll") \
        for (int h = 0; h < 2; ++h) { \
            int4v nb; \
            _Pragma("unroll") \
            for (int r2 = 0; r2 < 4; ++r2) { \
                const int mt_ = 2*h + (r2 >> 1), rr_ = 2*(r2 & 1); \
                nb[r2] = pkrtz_bits(acc[mt_][vt][rr_], acc[mt_][vt][rr_+1]); \
            } \
            Bf[vt][h] = __builtin_bit_cast(v8h, nb); } } }

    #pragma unroll 1
    for (int g = 0; g < NCHG; ++g) {
        if (g + 2 < NCHG) {
            GLDS16(ebase + (g + 2) * 256 + 4 * l, &ering[w][(g + 2) & 3][0]);
            asm volatile("s_waitcnt vmcnt(2)" ::: "memory");   // chunk g landed
        } else {
            asm volatile("s_waitcnt vmcnt(0)" ::: "memory");
        }
        const float* ep = &ering[w][g & 3][0];
        STEP(ep, g, 0) STEP(ep, g, 1) STEP(ep, g, 2) STEP(ep, g, 3)
    }

    if (l == 0) lsw[w] = ls;

    // ---- gold scores (all 512 threads) ----
    {
        const int*   tb  = tags + (size_t)b * SEQ;
        const float* ebm = emis + (size_t)b * SEQ * NT;
        const float* mbm = mask + (size_t)b * SEQ;
        float acg = 0.0f;
        for (int s = 1 + tid; s < SEQ; s += 512) {
            const int tc = tb[s];
            const int tp = tb[s - 1];
            acg += (ebm[(size_t)s * NT + tc] + trans[tp * NT + tc]) * mbm[s];
        }
        acg += __shfl_xor(acg, 32, 64); acg += __shfl_xor(acg, 16, 64);
        acg += __shfl_xor(acg,  8, 64); acg += __shfl_xor(acg,  4, 64);
        acg += __shfl_xor(acg,  2, 64); acg += __shfl_xor(acg,  1, 64);
        if (l == 0) gredw[w] = acg;
    }
    __syncthreads();

    // ---- stitch: 4 rounds; two half-waves produce partials, combine ----
    #pragma unroll 1
    for (int s = 0; s < NSEG; ++s) {
        if (seg == s) {
            float u4[2];
            #pragma unroll
            for (int vt = 0; vt < 2; ++vt) u4[vt] = ubuf[4*cc + 2*hf + vt];
            float p[16];
            #pragma unroll
            for (int h = 0; h < 2; ++h) {
                #pragma unroll
                for (int e = 0; e < 8; ++e) {
                    p[h*8 + e] = fmaf((float)Bf[0][h][e], u4[0],
                                      (float)Bf[1][h][e] * u4[1]);
                }
            }
            #pragma unroll
            for (int i = 0; i < 16; ++i) {
                DPP_ADD(p[i], 0x128) DPP_ADD(p[i], 0x124)
                DPP_ADD(p[i], 0x122) DPP_ADD(p[i], 0x121)
            }
            if (cc == 0) {
                #pragma unroll
                for (int h = 0; h < 2; ++h)
                    #pragma unroll
                    for (int e = 0; e < 8; ++e)
                        ph[hf][16*(2*h + (e>>2)) + 4*q + (e&3)] = p[h*8 + e];
            }
        }
        __syncthreads();
        if (w == 2*s) {
            const float dlt = lsw[2*s] - lsw[2*s + 1];
            float val = fmaf(exp2_hw(dlt), ph[1][l], ph[0][l]);
            float pm = val;
            pm = fmaxf(pm, __shfl_xor(pm, 32, 64)); pm = fmaxf(pm, __shfl_xor(pm, 16, 64));
            pm = fmaxf(pm, __shfl_xor(pm,  8, 64)); pm = fmaxf(pm, __shfl_xor(pm,  4, 64));
            pm = fmaxf(pm, __shfl_xor(pm,  2, 64)); pm = fmaxf(pm, __shfl_xor(pm,  1, 64));
            ubuf[l] = val / pm;
            if (l == 0) sigma_sh += lsw[2*s] + log2_hw(pm);
        }
        __syncthreads();
    }

    // ---- final: Z and output ----
    if (w == 0) {
        float su = ubuf[l];
        su += __shfl_xor(su, 32, 64); su += __shfl_xor(su, 16, 64);
        su += __shfl_xor(su,  8, 64); su += __shfl_xor(su,  4, 64);
        su += __shfl_xor(su,  2, 64); su += __shfl_xor(su,  1, 64);
        const float Z = LN2 * (sigma_sh + log2_hw(su));
        float gold = 0.0f;
        #pragma unroll
        for (int ww = 0; ww < 8; ++ww) gold += gredw[ww];
        if (l == 0)
            atomicAdd(out, (gold - Z) * (1.0f / BATCH));
    }
}

__global__ void zero_kernel(float* out) { if (threadIdx.x == 0) out[0] = 0.0f; }

extern "C" void kernel_launch(void* const* d_in, const int* in_sizes, int n_in,
                              void* d_out, int out_size, void* d_ws, size_t ws_size,
                              hipStream_t stream) {
    const float* emis  = (const float*)d_in[0];
    const int*   tags  = (const int*)d_in[1];
    const float* mask  = (const float*)d_in[2];
    const float* trans = (const float*)d_in[3];
    float* out = (float*)d_out;

    zero_kernel<<<1, 64, 0, stream>>>(out);
    crf_kernel<<<BATCH, 512, 0, stream>>>(emis, tags, mask, trans, out);
}